// Round 3
// baseline (572.141 us; speedup 1.0000x reference)
//
#include <hip/hip_runtime.h>

// Problem constants (fixed by setup_inputs)
#define BB 2
#define TT 2048
#define CC 1024
#define HH 16
#define DD 64
#define KDIM 1024
#define MROWS (BB*TT)   // 4096

typedef __attribute__((ext_vector_type(8))) short  frag_b16;  // 8 bf16 (4 VGPRs)
typedef __attribute__((ext_vector_type(4))) float  f32x4;
typedef __attribute__((ext_vector_type(4))) unsigned short us4;
typedef __attribute__((ext_vector_type(8))) unsigned short us8;
typedef __attribute__((ext_vector_type(4))) _Float16 f16x4;

__device__ __forceinline__ unsigned short f2bf(float f) {
    unsigned int u = __builtin_bit_cast(unsigned int, f);
    u += 0x7FFFu + ((u >> 16) & 1u);   // RNE
    return (unsigned short)(u >> 16);
}

// ---------------------------------------------------------------- fp32 -> bf16
__global__ __launch_bounds__(256) void cvt4(const float* __restrict__ src,
                                            unsigned short* __restrict__ dst, int n) {
    int i = (blockIdx.x * 256 + threadIdx.x) * 4;
    if (i >= n) return;
    float4 f = *reinterpret_cast<const float4*>(src + i);
    us4 o;
    o.x = f2bf(f.x); o.y = f2bf(f.y); o.z = f2bf(f.z); o.w = f2bf(f.w);
    *reinterpret_cast<us4*>(dst + i) = o;
}

// ------------------------------------------------- QKV projection (+RoPE) GEMM
__global__ __launch_bounds__(256) void qkv_gemm_rope(
        const unsigned short* __restrict__ X,
        const unsigned short* __restrict__ Wq,
        const unsigned short* __restrict__ Wk,
        const unsigned short* __restrict__ Wv,
        const float* __restrict__ bq, const float* __restrict__ bk,
        const float* __restrict__ bv,
        unsigned short* __restrict__ Qo,   // [B,H,T,D] bf16 (roped)
        unsigned short* __restrict__ Ko,   // [B,H,T,D] bf16 (roped)
        _Float16* __restrict__ VTo)        // [B,H,D,T] fp16
{
    const int z = blockIdx.z;
    const unsigned short* W = (z == 0) ? Wq : (z == 1) ? Wk : Wv;
    const float* bias = (z == 0) ? bq : (z == 1) ? bk : bv;

    const int wave = threadIdx.x >> 6;
    const int lane = threadIdx.x & 63;
    const int l16 = lane & 15;
    const int quad = lane >> 4;

    const int row0 = blockIdx.x * 128 + (wave >> 1) * 64;
    const int col0 = blockIdx.y * 128 + (wave & 1) * 64;

    f32x4 acc[4][4] = {};

    for (int kk = 0; kk < KDIM; kk += 32) {
        frag_b16 a[4], b[4];
#pragma unroll
        for (int r = 0; r < 4; ++r)
            a[r] = *reinterpret_cast<const frag_b16*>(
                X + (size_t)(row0 + r * 16 + l16) * KDIM + kk + quad * 8);
#pragma unroll
        for (int c = 0; c < 4; ++c)
            b[c] = *reinterpret_cast<const frag_b16*>(
                W + (size_t)(col0 + c * 16 + l16) * KDIM + kk + quad * 8);
#pragma unroll
        for (int r = 0; r < 4; ++r)
#pragma unroll
            for (int c = 0; c < 4; ++c)
                acc[r][c] = __builtin_amdgcn_mfma_f32_16x16x32_bf16(a[r], b[c], acc[r][c], 0, 0, 0);
    }

#pragma unroll
    for (int r = 0; r < 4; ++r) {
#pragma unroll
        for (int c = 0; c < 4; ++c) {
#pragma unroll
            for (int g = 0; g < 4; ++g) {
                int n = row0 + r * 16 + quad * 4 + g;
                int o = col0 + c * 16 + l16;
                float v = acc[r][c][g] + bias[o];
                int b_ = n >> 11;          // /T
                int t  = n & (TT - 1);
                int h  = o >> 6;
                int d  = o & (DD - 1);
                if (z == 2) {
                    VTo[(((size_t)(b_ * HH + h) * DD + d) * TT) + t] = (_Float16)v;
                } else {
                    float pv = __shfl_xor(v, 1);
                    float inv = __expf(-(float)(d & ~1) * (9.210340371976184f / (float)DD));
                    float ang = (float)t * inv;
                    float sn, cs;
                    __sincosf(ang, &sn, &cs);   // HW trig; args <= 2048 rad, err ~2e-4
                    float outv = (d & 1) ? (pv * sn + v * cs) : (v * cs - pv * sn);
                    unsigned short* dst = (z == 0) ? Qo : Ko;
                    dst[((size_t)(b_ * HH + h) * TT + t) * DD + d] = f2bf(outv);
                }
            }
        }
    }
}

// ------------------------------------------------------------ flash attention
// S^T = K·Q^T (16x16x32_bf16) so q = lane&15: softmax stats are lane-local
// (in-reg reduce + 2 shuffles). Y^T = V^T·P^T (16x16x16f16): the P^T
// B-fragment IS the S^T C-layout registers -> no LDS in the K-loop.
// 16 q-rows/wave, 4 waves/block (64 consecutive rows -> balanced trips),
// grid 32x32 = 4096 waves for occupancy; heavy blocks first (LPT).
__global__ __launch_bounds__(256, 4) void attn(
        const unsigned short* __restrict__ Q,
        const unsigned short* __restrict__ K,
        const _Float16* __restrict__ VT,
        unsigned short* __restrict__ Y)   // [B*T, C] bf16
{
    const int qblk = (int)(gridDim.x - 1 - blockIdx.x);   // heavy-first (LPT)
    const int bh = blockIdx.y;
    const int w = threadIdx.x >> 6;
    const int lane = threadIdx.x & 63;
    const int l16 = lane & 15;
    const int quad = lane >> 4;

    const int q0 = qblk * 64 + w * 16;
    const int q  = q0 + l16;

    const unsigned short* Qp = Q + (size_t)bh * TT * DD;
    const unsigned short* Kp = K + (size_t)bh * TT * DD;
    const _Float16* Vp = VT + (size_t)bh * DD * TT;

    __shared__ __align__(16) unsigned short Ylds[4][16][72];

    // Q fragments (B-operand of S^T): B[k=d=quad*8+j][n=q=l16]
    frag_b16 bq[2];
#pragma unroll
    for (int dk = 0; dk < 2; ++dk)
        bq[dk] = *reinterpret_cast<const frag_b16*>(
            Qp + (size_t)q * DD + dk * 32 + quad * 8);

    f32x4 yacc[4] = {};   // Y^T[d=dt*16+quad*4+g][q=l16]
    float m = -INFINITY, l = 0.f;

    const int keys_end = q0 + 16;   // exclusive causal bound for this wave
    for (int j0 = 0; j0 < keys_end; j0 += 64) {
        // K fragments (A-operand): A[m=key=l16][k=d=quad*8+j]
        frag_b16 ak[4][2];
#pragma unroll
        for (int mt = 0; mt < 4; ++mt)
#pragma unroll
            for (int dk = 0; dk < 2; ++dk)
                ak[mt][dk] = *reinterpret_cast<const frag_b16*>(
                    Kp + (size_t)(j0 + mt * 16 + l16) * DD + dk * 32 + quad * 8);

        // S^T[key][q]
        f32x4 s[4] = {};
#pragma unroll
        for (int mt = 0; mt < 4; ++mt) {
            s[mt] = __builtin_amdgcn_mfma_f32_16x16x32_bf16(ak[mt][0], bq[0], s[mt], 0, 0, 0);
            s[mt] = __builtin_amdgcn_mfma_f32_16x16x32_bf16(ak[mt][1], bq[1], s[mt], 0, 0, 0);
        }

        // V^T fragments (A-operand of PV): A[m=d=l16][k=key=quad*4+j]
        f16x4 av[4][4];
#pragma unroll
        for (int dt = 0; dt < 4; ++dt)
#pragma unroll
            for (int kt = 0; kt < 4; ++kt)
                av[dt][kt] = *reinterpret_cast<const f16x4*>(
                    Vp + (size_t)(dt * 16 + l16) * TT + j0 + kt * 16 + quad * 4);

        // scale + causal mask + row max (q lane-local, key in regs)
        float nm = -INFINITY;
#pragma unroll
        for (int mt = 0; mt < 4; ++mt)
#pragma unroll
            for (int g = 0; g < 4; ++g) {
                int key = j0 + mt * 16 + quad * 4 + g;
                float v = s[mt][g] * 0.125f;
                if (key > q) v = -1e30f;
                s[mt][g] = v;
                nm = fmaxf(nm, v);
            }
        nm = fmaxf(nm, __shfl_xor(nm, 16));
        nm = fmaxf(nm, __shfl_xor(nm, 32));

        float mn = fmaxf(m, nm);
        float alpha = __expf(m - mn);
        m = mn;

        float rs = 0.f;
#pragma unroll
        for (int mt = 0; mt < 4; ++mt)
#pragma unroll
            for (int g = 0; g < 4; ++g) {
                float e = __expf(s[mt][g] - m);
                s[mt][g] = e;
                rs += e;
            }
        rs += __shfl_xor(rs, 16);
        rs += __shfl_xor(rs, 32);
        l = l * alpha + rs;

        // pack P^T to fp16 B-fragments: B[k=key=quad*4+j][n=q=l16]
        f16x4 pb[4];
#pragma unroll
        for (int kt = 0; kt < 4; ++kt)
#pragma unroll
            for (int g = 0; g < 4; ++g)
                pb[kt][g] = (_Float16)s[kt][g];

        // rescale + accumulate Y^T
#pragma unroll
        for (int dt = 0; dt < 4; ++dt) {
            f32x4 ya = yacc[dt];
#pragma unroll
            for (int g = 0; g < 4; ++g) ya[g] *= alpha;
#pragma unroll
            for (int kt = 0; kt < 4; ++kt)
                ya = __builtin_amdgcn_mfma_f32_16x16x16f16(av[dt][kt], pb[kt], ya, 0, 0, 0);
            yacc[dt] = ya;
        }
    }

    // epilogue: normalize, LDS transpose (per-wave buffer), coalesced stores
    float rl = 1.f / l;
#pragma unroll
    for (int dt = 0; dt < 4; ++dt)
#pragma unroll
        for (int g = 0; g < 4; ++g)
            Ylds[w][l16][dt * 16 + quad * 4 + g] = f2bf(yacc[dt][g] * rl);

    __syncthreads();

    const int b_ = bh >> 4, h = bh & (HH - 1);
    const int tl = lane >> 3;          // 0..7: token within group of 8
    const int c8 = (lane & 7) * 8;     // 16B column chunk
#pragma unroll
    for (int i = 0; i < 2; ++i) {
        int tok = i * 8 + tl;
        us8 v = *reinterpret_cast<const us8*>(&Ylds[w][tok][c8]);
        *reinterpret_cast<us8*>(
            &Y[(size_t)(b_ * TT + q0 + tok) * CC + h * DD + c8]) = v;
    }
}

// --------------------------------------------------------- output projection
__global__ __launch_bounds__(256) void out_gemm(
        const unsigned short* __restrict__ Y,
        const unsigned short* __restrict__ Wo,
        const float* __restrict__ bo,
        float* __restrict__ out)
{
    const int wave = threadIdx.x >> 6;
    const int lane = threadIdx.x & 63;
    const int l16 = lane & 15;
    const int quad = lane >> 4;

    const int row0 = blockIdx.x * 128 + (wave >> 1) * 64;
    const int col0 = blockIdx.y * 128 + (wave & 1) * 64;

    f32x4 acc[4][4] = {};

    for (int kk = 0; kk < KDIM; kk += 32) {
        frag_b16 a[4], b[4];
#pragma unroll
        for (int r = 0; r < 4; ++r)
            a[r] = *reinterpret_cast<const frag_b16*>(
                Y + (size_t)(row0 + r * 16 + l16) * KDIM + kk + quad * 8);
#pragma unroll
        for (int c = 0; c < 4; ++c)
            b[c] = *reinterpret_cast<const frag_b16*>(
                Wo + (size_t)(col0 + c * 16 + l16) * KDIM + kk + quad * 8);
#pragma unroll
        for (int r = 0; r < 4; ++r)
#pragma unroll
            for (int c = 0; c < 4; ++c)
                acc[r][c] = __builtin_amdgcn_mfma_f32_16x16x32_bf16(a[r], b[c], acc[r][c], 0, 0, 0);
    }

#pragma unroll
    for (int r = 0; r < 4; ++r)
#pragma unroll
        for (int c = 0; c < 4; ++c)
#pragma unroll
            for (int g = 0; g < 4; ++g) {
                int n = row0 + r * 16 + quad * 4 + g;
                int o = col0 + c * 16 + l16;
                out[(size_t)n * CC + o] = acc[r][c][g] + bo[o];
            }
}

// ---------------------------------------------------------------------- launch
extern "C" void kernel_launch(void* const* d_in, const int* in_sizes, int n_in,
                              void* d_out, int out_size, void* d_ws, size_t ws_size,
                              hipStream_t stream) {
    const float* x  = (const float*)d_in[0];
    const float* Wq = (const float*)d_in[1];
    const float* bq = (const float*)d_in[2];
    const float* Wk = (const float*)d_in[3];
    const float* bk = (const float*)d_in[4];
    const float* Wv = (const float*)d_in[5];
    const float* bv = (const float*)d_in[6];
    const float* Wo = (const float*)d_in[7];
    const float* bo = (const float*)d_in[8];
    float* out = (float*)d_out;

    unsigned short* ws = (unsigned short*)d_ws;
    const size_t NX = (size_t)MROWS * CC;      // 4194304
    const size_t NW = (size_t)CC * CC;         // 1048576
    unsigned short* xb  = ws;
    unsigned short* wqb = xb  + NX;
    unsigned short* wkb = wqb + NW;
    unsigned short* wvb = wkb + NW;
    unsigned short* wob = wvb + NW;
    unsigned short* Qr  = wob + NW;
    unsigned short* Kr  = Qr  + NX;
    _Float16*       VTb = (_Float16*)(Kr + NX);
    unsigned short* Yb  = (unsigned short*)(VTb + NX);

    cvt4<<<dim3((unsigned)(NX / 1024)), 256, 0, stream>>>(x,  xb,  (int)NX);
    cvt4<<<dim3((unsigned)(NW / 1024)), 256, 0, stream>>>(Wq, wqb, (int)NW);
    cvt4<<<dim3((unsigned)(NW / 1024)), 256, 0, stream>>>(Wk, wkb, (int)NW);
    cvt4<<<dim3((unsigned)(NW / 1024)), 256, 0, stream>>>(Wv, wvb, (int)NW);
    cvt4<<<dim3((unsigned)(NW / 1024)), 256, 0, stream>>>(Wo, wob, (int)NW);

    qkv_gemm_rope<<<dim3(MROWS / 128, CC / 128, 3), 256, 0, stream>>>(
        xb, wqb, wkb, wvb, bq, bk, bv, Qr, Kr, VTb);

    attn<<<dim3(TT / 64, BB * HH), 256, 0, stream>>>(Qr, Kr, VTb, Yb);

    out_gemm<<<dim3(MROWS / 128, CC / 128), 256, 0, stream>>>(Yb, wob, bo, out);
}

// Round 4
// 380.653 us; speedup vs baseline: 1.5031x; 1.5031x over previous
//
#include <hip/hip_runtime.h>

// Problem constants (fixed by setup_inputs)
#define BB 2
#define TT 2048
#define CC 1024
#define HH 16
#define DD 64
#define KDIM 1024
#define MROWS (BB*TT)   // 4096

typedef __attribute__((ext_vector_type(8))) short  frag_b16;  // 8 bf16 (4 VGPRs)
typedef __attribute__((ext_vector_type(4))) float  f32x4;
typedef __attribute__((ext_vector_type(4))) unsigned short us4;
typedef __attribute__((ext_vector_type(8))) unsigned short us8;
typedef __attribute__((ext_vector_type(4))) _Float16 f16x4;
typedef __attribute__((ext_vector_type(8))) _Float16 f16x8;

__device__ __forceinline__ unsigned short f2bf(float f) {
    unsigned int u = __builtin_bit_cast(unsigned int, f);
    u += 0x7FFFu + ((u >> 16) & 1u);   // RNE
    return (unsigned short)(u >> 16);
}

// ---------------------------------------------------------------- fp32 -> bf16
__global__ __launch_bounds__(256) void cvt4(const float* __restrict__ src,
                                            unsigned short* __restrict__ dst, int n) {
    int i = (blockIdx.x * 256 + threadIdx.x) * 4;
    if (i >= n) return;
    float4 f = *reinterpret_cast<const float4*>(src + i);
    us4 o;
    o.x = f2bf(f.x); o.y = f2bf(f.y); o.z = f2bf(f.z); o.w = f2bf(f.w);
    *reinterpret_cast<us4*>(dst + i) = o;
}

// ------------------------------------------------- QKV projection (+RoPE) GEMM
// V^T is emitted via a per-wave LDS transpose so the global stores are
// coalesced 16B chunks along t (direct store was a 2B/4KB-stride scatter ->
// 124 MB of HBM writes).
__global__ __launch_bounds__(256) void qkv_gemm_rope(
        const unsigned short* __restrict__ X,
        const unsigned short* __restrict__ Wq,
        const unsigned short* __restrict__ Wk,
        const unsigned short* __restrict__ Wv,
        const float* __restrict__ bq, const float* __restrict__ bk,
        const float* __restrict__ bv,
        unsigned short* __restrict__ Qo,   // [B,H,T,D] bf16 (roped)
        unsigned short* __restrict__ Ko,   // [B,H,T,D] bf16 (roped)
        _Float16* __restrict__ VTo)        // [B,H,D,T] fp16
{
    const int z = blockIdx.z;
    const unsigned short* W = (z == 0) ? Wq : (z == 1) ? Wk : Wv;
    const float* bias = (z == 0) ? bq : (z == 1) ? bk : bv;

    const int wave = threadIdx.x >> 6;
    const int lane = threadIdx.x & 63;
    const int l16 = lane & 15;
    const int quad = lane >> 4;

    const int row0 = blockIdx.x * 128 + (wave >> 1) * 64;
    const int col0 = blockIdx.y * 128 + (wave & 1) * 64;

    __shared__ _Float16 Vl[4][64][72];   // [wave][d][t_local], row = 144B (16B mult)

    f32x4 acc[4][4] = {};

    for (int kk = 0; kk < KDIM; kk += 32) {
        frag_b16 a[4], b[4];
#pragma unroll
        for (int r = 0; r < 4; ++r)
            a[r] = *reinterpret_cast<const frag_b16*>(
                X + (size_t)(row0 + r * 16 + l16) * KDIM + kk + quad * 8);
#pragma unroll
        for (int c = 0; c < 4; ++c)
            b[c] = *reinterpret_cast<const frag_b16*>(
                W + (size_t)(col0 + c * 16 + l16) * KDIM + kk + quad * 8);
#pragma unroll
        for (int r = 0; r < 4; ++r)
#pragma unroll
            for (int c = 0; c < 4; ++c)
                acc[r][c] = __builtin_amdgcn_mfma_f32_16x16x32_bf16(a[r], b[c], acc[r][c], 0, 0, 0);
    }

    if (z == 2) {
        // V: LDS transpose then coalesced V^T stores.
        // Wave tile = 64 tokens (rows) x 64 dims (one head, col0 is 64-aligned).
#pragma unroll
        for (int r = 0; r < 4; ++r)
#pragma unroll
            for (int c = 0; c < 4; ++c) {
                f16x4 pk;
#pragma unroll
                for (int g = 0; g < 4; ++g)
                    pk[g] = (_Float16)(acc[r][c][g] + bias[col0 + c * 16 + l16]);
                *reinterpret_cast<f16x4*>(&Vl[wave][c * 16 + l16][r * 16 + quad * 4]) = pk;
            }
        const int b_ = row0 >> 11;
        const int t_base = row0 & (TT - 1);
        const int h = col0 >> 6;
        const int dl = lane >> 3;          // 0..7
        const int t8 = (lane & 7) * 8;     // 16B chunk along t
#pragma unroll
        for (int i = 0; i < 8; ++i) {
            int d = i * 8 + dl;
            f16x8 v = *reinterpret_cast<const f16x8*>(&Vl[wave][d][t8]);
            *reinterpret_cast<f16x8*>(
                &VTo[((size_t)(b_ * HH + h) * DD + d) * TT + t_base + t8]) = v;
        }
    } else {
#pragma unroll
        for (int r = 0; r < 4; ++r)
#pragma unroll
            for (int c = 0; c < 4; ++c)
#pragma unroll
                for (int g = 0; g < 4; ++g) {
                    int n = row0 + r * 16 + quad * 4 + g;
                    int o = col0 + c * 16 + l16;
                    float v = acc[r][c][g] + bias[o];
                    int b_ = n >> 11;
                    int t  = n & (TT - 1);
                    int h  = o >> 6;
                    int d  = o & (DD - 1);
                    float pv = __shfl_xor(v, 1);
                    float inv = __expf(-(float)(d & ~1) * (9.210340371976184f / (float)DD));
                    float ang = (float)t * inv;
                    float sn, cs;
                    __sincosf(ang, &sn, &cs);
                    float outv = (d & 1) ? (pv * sn + v * cs) : (v * cs - pv * sn);
                    unsigned short* dst = (z == 0) ? Qo : Ko;
                    dst[((size_t)(b_ * HH + h) * TT + t) * DD + d] = f2bf(outv);
                }
    }
}

// ------------------------------------------------------------ flash attention
// Split-K: block = one 32-row q-tile, 4 waves; wave w takes key tiles
// w, w+4, ... (32 keys each, round-robin -> balanced +-1). Each wave runs its
// own online softmax (S^T = K·Q^T so q=lane&15: stats lane-local, P^T stays
// in registers for Y^T = V^T·P^T). Per-block merge of (m,l,Y) through LDS.
// Critical path drops 4x vs one-wave-per-tile; 8192 waves for latency hiding.
__global__ __launch_bounds__(256, 4) void attn(
        const unsigned short* __restrict__ Q,
        const unsigned short* __restrict__ K,
        const _Float16* __restrict__ VT,
        unsigned short* __restrict__ Y)   // [B*T, C] bf16
{
    const int qblk = (int)(gridDim.x - 1 - blockIdx.x);   // heavy-first (LPT)
    const int bh = blockIdx.y;
    const int w = threadIdx.x >> 6;
    const int lane = threadIdx.x & 63;
    const int l16 = lane & 15;
    const int quad = lane >> 4;

    const int q0 = qblk * 32;

    const unsigned short* Qp = Q + (size_t)bh * TT * DD;
    const unsigned short* Kp = K + (size_t)bh * TT * DD;
    const _Float16* Vp = VT + (size_t)bh * DD * TT;

    __shared__ float Ml[4][2][16];
    __shared__ float Ll[4][2][16];
    __shared__ __align__(16) float Yl[32][68];   // row = 272B (16B mult), pad kills conflicts

    // Q fragments (B-operand of S^T): B[k=d=quad*8+j][n=q=l16]
    frag_b16 bq[2][2];
#pragma unroll
    for (int nt = 0; nt < 2; ++nt)
#pragma unroll
        for (int dk = 0; dk < 2; ++dk)
            bq[nt][dk] = *reinterpret_cast<const frag_b16*>(
                Qp + (size_t)(q0 + nt * 16 + l16) * DD + dk * 32 + quad * 8);

    f32x4 yacc[2][4] = {};   // Y^T[d=dt*16+quad*4+g][q=nt*16+l16]
    float m[2] = { -INFINITY, -INFINITY }, l[2] = { 0.f, 0.f };

    const int tiles = qblk + 1;   // 32-key tiles in causal range
    for (int it = w; it < tiles; it += 4) {
        const int j0 = it * 32;
        // K fragments (A-operand): A[m=key=l16][k=d=quad*8+j]
        frag_b16 ak[2][2];
#pragma unroll
        for (int mt = 0; mt < 2; ++mt)
#pragma unroll
            for (int dk = 0; dk < 2; ++dk)
                ak[mt][dk] = *reinterpret_cast<const frag_b16*>(
                    Kp + (size_t)(j0 + mt * 16 + l16) * DD + dk * 32 + quad * 8);

        // V^T fragments (A-operand of PV): A[m=d=l16][k=key=quad*4+j]
        f16x4 av[4][2];
#pragma unroll
        for (int dt = 0; dt < 4; ++dt)
#pragma unroll
            for (int kt = 0; kt < 2; ++kt)
                av[dt][kt] = *reinterpret_cast<const f16x4*>(
                    Vp + (size_t)(dt * 16 + l16) * TT + j0 + kt * 16 + quad * 4);

        // S^T[key][q]
        f32x4 s[2][2] = {};
#pragma unroll
        for (int mt = 0; mt < 2; ++mt)
#pragma unroll
            for (int nt = 0; nt < 2; ++nt) {
                s[mt][nt] = __builtin_amdgcn_mfma_f32_16x16x32_bf16(ak[mt][0], bq[nt][0], s[mt][nt], 0, 0, 0);
                s[mt][nt] = __builtin_amdgcn_mfma_f32_16x16x32_bf16(ak[mt][1], bq[nt][1], s[mt][nt], 0, 0, 0);
            }

        // scale + causal mask + row max (every tile has >=1 valid key per row)
        float nm[2] = { -INFINITY, -INFINITY };
#pragma unroll
        for (int mt = 0; mt < 2; ++mt)
#pragma unroll
            for (int nt = 0; nt < 2; ++nt)
#pragma unroll
                for (int g = 0; g < 4; ++g) {
                    int key = j0 + mt * 16 + quad * 4 + g;
                    int q   = q0 + nt * 16 + l16;
                    float v = s[mt][nt][g] * 0.125f;
                    if (key > q) v = -1e30f;
                    s[mt][nt][g] = v;
                    nm[nt] = fmaxf(nm[nt], v);
                }
#pragma unroll
        for (int nt = 0; nt < 2; ++nt) {
            nm[nt] = fmaxf(nm[nt], __shfl_xor(nm[nt], 16));
            nm[nt] = fmaxf(nm[nt], __shfl_xor(nm[nt], 32));
        }

        float alpha[2];
#pragma unroll
        for (int nt = 0; nt < 2; ++nt) {
            float mn = fmaxf(m[nt], nm[nt]);
            alpha[nt] = __expf(m[nt] - mn);
            m[nt] = mn;
        }

        float rs[2] = { 0.f, 0.f };
#pragma unroll
        for (int mt = 0; mt < 2; ++mt)
#pragma unroll
            for (int nt = 0; nt < 2; ++nt)
#pragma unroll
                for (int g = 0; g < 4; ++g) {
                    float e = __expf(s[mt][nt][g] - m[nt]);
                    s[mt][nt][g] = e;
                    rs[nt] += e;
                }
#pragma unroll
        for (int nt = 0; nt < 2; ++nt) {
            rs[nt] += __shfl_xor(rs[nt], 16);
            rs[nt] += __shfl_xor(rs[nt], 32);
            l[nt] = l[nt] * alpha[nt] + rs[nt];
        }

        // pack P^T to fp16 B-fragments: B[k=key=quad*4+j][n=q=l16]
        f16x4 pb[2][2];
#pragma unroll
        for (int kt = 0; kt < 2; ++kt)
#pragma unroll
            for (int nt = 0; nt < 2; ++nt)
#pragma unroll
                for (int g = 0; g < 4; ++g)
                    pb[kt][nt][g] = (_Float16)s[kt][nt][g];

        // rescale + accumulate Y^T
#pragma unroll
        for (int nt = 0; nt < 2; ++nt)
#pragma unroll
            for (int dt = 0; dt < 4; ++dt) {
                f32x4 ya = yacc[nt][dt];
#pragma unroll
                for (int g = 0; g < 4; ++g) ya[g] *= alpha[nt];
                ya = __builtin_amdgcn_mfma_f32_16x16x16f16(av[dt][0], pb[0][nt], ya, 0, 0, 0);
                ya = __builtin_amdgcn_mfma_f32_16x16x16f16(av[dt][1], pb[1][nt], ya, 0, 0, 0);
                yacc[nt][dt] = ya;
            }
    }

    // ------- merge the 4 split-K partials -------
    if (quad == 0) {
#pragma unroll
        for (int nt = 0; nt < 2; ++nt) {
            Ml[w][nt][l16] = m[nt];
            Ll[w][nt][l16] = l[nt];
        }
    }
    __syncthreads();

    float beta[2];
#pragma unroll
    for (int nt = 0; nt < 2; ++nt) {
        float gm = -INFINITY;
#pragma unroll
        for (int w2 = 0; w2 < 4; ++w2) gm = fmaxf(gm, Ml[w2][nt][l16]);
        beta[nt] = __expf(m[nt] - gm);   // 0 for waves with no iterations
    }

#pragma unroll
    for (int t = 0; t < 4; ++t) {
        if (w == t) {
#pragma unroll
            for (int nt = 0; nt < 2; ++nt)
#pragma unroll
                for (int dt = 0; dt < 4; ++dt) {
                    float* p = &Yl[nt * 16 + l16][dt * 16 + quad * 4];
                    f32x4 cur;
                    if (t == 0) cur = f32x4{0.f, 0.f, 0.f, 0.f};
                    else        cur = *reinterpret_cast<f32x4*>(p);
#pragma unroll
                    for (int g = 0; g < 4; ++g) cur[g] += beta[nt] * yacc[nt][dt][g];
                    *reinterpret_cast<f32x4*>(p) = cur;
                }
        }
        __syncthreads();
    }

    // ------- normalize + coalesced store (256 threads over 32x64 tile) -------
    const int tok = threadIdx.x >> 3;        // 0..31
    const int d8  = (threadIdx.x & 7) * 8;   // 16B-of-bf16 chunk
    const int ntk = tok >> 4, lk = tok & 15;
    float gm = -INFINITY;
#pragma unroll
    for (int w2 = 0; w2 < 4; ++w2) gm = fmaxf(gm, Ml[w2][ntk][lk]);
    float gl = 0.f;
#pragma unroll
    for (int w2 = 0; w2 < 4; ++w2) gl += Ll[w2][ntk][lk] * __expf(Ml[w2][ntk][lk] - gm);
    const float inv = 1.f / gl;

    const int b_ = bh >> 4, h = bh & (HH - 1);
    us8 ov;
#pragma unroll
    for (int g = 0; g < 8; ++g) ov[g] = f2bf(Yl[tok][d8 + g] * inv);
    *reinterpret_cast<us8*>(&Y[(size_t)(b_ * TT + q0 + tok) * CC + h * DD + d8]) = ov;
}

// --------------------------------------------------------- output projection
__global__ __launch_bounds__(256) void out_gemm(
        const unsigned short* __restrict__ Y,
        const unsigned short* __restrict__ Wo,
        const float* __restrict__ bo,
        float* __restrict__ out)
{
    const int wave = threadIdx.x >> 6;
    const int lane = threadIdx.x & 63;
    const int l16 = lane & 15;
    const int quad = lane >> 4;

    const int row0 = blockIdx.x * 128 + (wave >> 1) * 64;
    const int col0 = blockIdx.y * 128 + (wave & 1) * 64;

    f32x4 acc[4][4] = {};

    for (int kk = 0; kk < KDIM; kk += 32) {
        frag_b16 a[4], b[4];
#pragma unroll
        for (int r = 0; r < 4; ++r)
            a[r] = *reinterpret_cast<const frag_b16*>(
                Y + (size_t)(row0 + r * 16 + l16) * KDIM + kk + quad * 8);
#pragma unroll
        for (int c = 0; c < 4; ++c)
            b[c] = *reinterpret_cast<const frag_b16*>(
                Wo + (size_t)(col0 + c * 16 + l16) * KDIM + kk + quad * 8);
#pragma unroll
        for (int r = 0; r < 4; ++r)
#pragma unroll
            for (int c = 0; c < 4; ++c)
                acc[r][c] = __builtin_amdgcn_mfma_f32_16x16x32_bf16(a[r], b[c], acc[r][c], 0, 0, 0);
    }

#pragma unroll
    for (int r = 0; r < 4; ++r)
#pragma unroll
        for (int c = 0; c < 4; ++c)
#pragma unroll
            for (int g = 0; g < 4; ++g) {
                int n = row0 + r * 16 + quad * 4 + g;
                int o = col0 + c * 16 + l16;
                out[(size_t)n * CC + o] = acc[r][c][g] + bo[o];
            }
}

// ---------------------------------------------------------------------- launch
extern "C" void kernel_launch(void* const* d_in, const int* in_sizes, int n_in,
                              void* d_out, int out_size, void* d_ws, size_t ws_size,
                              hipStream_t stream) {
    const float* x  = (const float*)d_in[0];
    const float* Wq = (const float*)d_in[1];
    const float* bq = (const float*)d_in[2];
    const float* Wk = (const float*)d_in[3];
    const float* bk = (const float*)d_in[4];
    const float* Wv = (const float*)d_in[5];
    const float* bv = (const float*)d_in[6];
    const float* Wo = (const float*)d_in[7];
    const float* bo = (const float*)d_in[8];
    float* out = (float*)d_out;

    unsigned short* ws = (unsigned short*)d_ws;
    const size_t NX = (size_t)MROWS * CC;      // 4194304
    const size_t NW = (size_t)CC * CC;         // 1048576
    unsigned short* xb  = ws;
    unsigned short* wqb = xb  + NX;
    unsigned short* wkb = wqb + NW;
    unsigned short* wvb = wkb + NW;
    unsigned short* wob = wvb + NW;
    unsigned short* Qr  = wob + NW;
    unsigned short* Kr  = Qr  + NX;
    _Float16*       VTb = (_Float16*)(Kr + NX);
    unsigned short* Yb  = (unsigned short*)(VTb + NX);

    cvt4<<<dim3((unsigned)(NX / 1024)), 256, 0, stream>>>(x,  xb,  (int)NX);
    cvt4<<<dim3((unsigned)(NW / 1024)), 256, 0, stream>>>(Wq, wqb, (int)NW);
    cvt4<<<dim3((unsigned)(NW / 1024)), 256, 0, stream>>>(Wk, wkb, (int)NW);
    cvt4<<<dim3((unsigned)(NW / 1024)), 256, 0, stream>>>(Wv, wvb, (int)NW);
    cvt4<<<dim3((unsigned)(NW / 1024)), 256, 0, stream>>>(Wo, wob, (int)NW);

    qkv_gemm_rope<<<dim3(MROWS / 128, CC / 128, 3), 256, 0, stream>>>(
        xb, wqb, wkb, wvb, bq, bk, bv, Qr, Kr, VTb);

    attn<<<dim3(TT / 32, BB * HH), 256, 0, stream>>>(Qr, Kr, VTb, Yb);

    out_gemm<<<dim3(MROWS / 128, CC / 128), 256, 0, stream>>>(Yb, wob, bo, out);
}

// Round 5
// 212.706 us; speedup vs baseline: 2.6898x; 1.7896x over previous
//
#include <hip/hip_runtime.h>

// Problem constants (fixed by setup_inputs)
#define BB 2
#define TT 2048
#define CC 1024
#define HH 16
#define DD 64
#define KDIM 1024
#define MROWS (BB*TT)   // 4096

typedef __attribute__((ext_vector_type(8))) short  frag_b16;  // 8 bf16 (4 VGPRs)
typedef __attribute__((ext_vector_type(4))) float  f32x4;
typedef __attribute__((ext_vector_type(4))) unsigned short us4;
typedef __attribute__((ext_vector_type(8))) unsigned short us8;
typedef __attribute__((ext_vector_type(4))) _Float16 f16x4;
typedef __attribute__((ext_vector_type(8))) _Float16 f16x8;

__device__ __forceinline__ unsigned short f2bf(float f) {
    unsigned int u = __builtin_bit_cast(unsigned int, f);
    u += 0x7FFFu + ((u >> 16) & 1u);   // RNE
    return (unsigned short)(u >> 16);
}

// async global->LDS, 16B per lane. LDS dest must be lane-linear (HW uses
// wave-uniform base + lane*16); our chunk index is linear in threadIdx.
__device__ __forceinline__ void gl_lds16(const void* g, void* l) {
    __builtin_amdgcn_global_load_lds(
        (const __attribute__((address_space(1))) unsigned int*)g,
        (__attribute__((address_space(3))) unsigned int*)l, 16, 0, 0);
}

// ---------------------------------------------------------------- fp32 -> bf16
__global__ __launch_bounds__(256) void cvt4(const float* __restrict__ src,
                                            unsigned short* __restrict__ dst, int n) {
    int i = (blockIdx.x * 256 + threadIdx.x) * 4;
    if (i >= n) return;
    float4 f = *reinterpret_cast<const float4*>(src + i);
    us4 o;
    o.x = f2bf(f.x); o.y = f2bf(f.y); o.z = f2bf(f.z); o.w = f2bf(f.w);
    *reinterpret_cast<us4*>(dst + i) = o;
}

// ------------------------------------------------- QKV projection (+RoPE) GEMM
// m97 anatomy: per 32-K step, stage X[128][32] + W[128][32] into LDS with
// global_load_lds(16B), 2 barriers, ds_read_b128 fragments.
__global__ __launch_bounds__(256, 2) void qkv_gemm_rope(
        const unsigned short* __restrict__ X,
        const unsigned short* __restrict__ Wq,
        const unsigned short* __restrict__ Wk,
        const unsigned short* __restrict__ Wv,
        const float* __restrict__ bq, const float* __restrict__ bk,
        const float* __restrict__ bv,
        unsigned short* __restrict__ Qo,   // [B,H,T,D] bf16 (roped)
        unsigned short* __restrict__ Ko,   // [B,H,T,D] bf16 (roped)
        _Float16* __restrict__ VTo)        // [B,H,D,T] fp16
{
    const int z = blockIdx.z;
    const unsigned short* W = (z == 0) ? Wq : (z == 1) ? Wk : Wv;
    const float* bias = (z == 0) ? bq : (z == 1) ? bk : bv;

    const int tid = threadIdx.x;
    const int wave = tid >> 6;
    const int lane = tid & 63;
    const int l16 = lane & 15;
    const int quad = lane >> 4;

    const int bx = blockIdx.x * 128;
    const int by = blockIdx.y * 128;
    const int row0 = bx + (wave >> 1) * 64;
    const int col0 = by + (wave & 1) * 64;

    __shared__ unsigned short Xa[128][32];
    __shared__ unsigned short Wb[128][32];
    __shared__ _Float16 Vl[4][64][72];   // z==2 transpose scratch (16B-mult rows)

    f32x4 acc[4][4] = {};

    const int c0 = tid, c1 = tid + 256;
    const int r0s = c0 >> 2, o0s = (c0 & 3) * 8;
    const int r1s = c1 >> 2, o1s = (c1 & 3) * 8;

    for (int kk = 0; kk < KDIM; kk += 32) {
        gl_lds16(X + (size_t)(bx + r0s) * KDIM + kk + o0s, (unsigned short*)Xa + c0 * 8);
        gl_lds16(X + (size_t)(bx + r1s) * KDIM + kk + o1s, (unsigned short*)Xa + c1 * 8);
        gl_lds16(W + (size_t)(by + r0s) * KDIM + kk + o0s, (unsigned short*)Wb + c0 * 8);
        gl_lds16(W + (size_t)(by + r1s) * KDIM + kk + o1s, (unsigned short*)Wb + c1 * 8);
        __syncthreads();

        frag_b16 a[4], b[4];
#pragma unroll
        for (int r = 0; r < 4; ++r)
            a[r] = *reinterpret_cast<const frag_b16*>(
                &Xa[(wave >> 1) * 64 + r * 16 + l16][quad * 8]);
#pragma unroll
        for (int c = 0; c < 4; ++c)
            b[c] = *reinterpret_cast<const frag_b16*>(
                &Wb[(wave & 1) * 64 + c * 16 + l16][quad * 8]);
#pragma unroll
        for (int r = 0; r < 4; ++r)
#pragma unroll
            for (int c = 0; c < 4; ++c)
                acc[r][c] = __builtin_amdgcn_mfma_f32_16x16x32_bf16(a[r], b[c], acc[r][c], 0, 0, 0);
        __syncthreads();
    }

    if (z == 2) {
        // V: per-wave LDS transpose then coalesced V^T stores (64 tok x 64 d).
#pragma unroll
        for (int r = 0; r < 4; ++r)
#pragma unroll
            for (int c = 0; c < 4; ++c) {
                f16x4 pk;
#pragma unroll
                for (int g = 0; g < 4; ++g)
                    pk[g] = (_Float16)(acc[r][c][g] + bias[col0 + c * 16 + l16]);
                *reinterpret_cast<f16x4*>(&Vl[wave][c * 16 + l16][r * 16 + quad * 4]) = pk;
            }
        const int b_ = row0 >> 11;
        const int t_base = row0 & (TT - 1);
        const int h = col0 >> 6;
        const int dl = lane >> 3;          // 0..7
        const int t8 = (lane & 7) * 8;     // 16B chunk along t
        __builtin_amdgcn_s_waitcnt(0);     // drain own ds_writes (wave-private buf)
#pragma unroll
        for (int i = 0; i < 8; ++i) {
            int d = i * 8 + dl;
            f16x8 v = *reinterpret_cast<const f16x8*>(&Vl[wave][d][t8]);
            *reinterpret_cast<f16x8*>(
                &VTo[((size_t)(b_ * HH + h) * DD + d) * TT + t_base + t8]) = v;
        }
    } else {
#pragma unroll
        for (int r = 0; r < 4; ++r)
#pragma unroll
            for (int c = 0; c < 4; ++c)
#pragma unroll
                for (int g = 0; g < 4; ++g) {
                    int n = row0 + r * 16 + quad * 4 + g;
                    int o = col0 + c * 16 + l16;
                    float v = acc[r][c][g] + bias[o];
                    int b_ = n >> 11;
                    int t  = n & (TT - 1);
                    int h  = o >> 6;
                    int d  = o & (DD - 1);
                    float pv = __shfl_xor(v, 1);
                    float inv = __expf(-(float)(d & ~1) * (9.210340371976184f / (float)DD));
                    float ang = (float)t * inv;
                    float sn, cs;
                    __sincosf(ang, &sn, &cs);
                    float outv = (d & 1) ? (pv * sn + v * cs) : (v * cs - pv * sn);
                    unsigned short* dst = (z == 0) ? Qo : Ko;
                    dst[((size_t)(b_ * HH + h) * TT + t) * DD + d] = f2bf(outv);
                }
    }
}

// ------------------------------------------------------------ flash attention
// Block = 64 q-rows x 4 waves (16 q each; q=lane&15 -> lane-local softmax
// stats). K-loop: stage 64-key K tile (bf16 [key][d]) + V tile (fp16 [d][t])
// into LDS via global_load_lds, XOR-swizzled through the GLOBAL gather index
// (LDS dest must stay lane-linear): physical chunk [row][c] holds logical
// [row][c^(row&7)], making fragment ds_reads ~2-way conflict (free).
// P^T stays in registers (S^T C-layout == PV B-fragment). Mask only on the
// diagonal tile. Uniform trips per block; LPT heavy-first.
__global__ __launch_bounds__(256, 4) void attn(
        const unsigned short* __restrict__ Q,
        const unsigned short* __restrict__ K,
        const _Float16* __restrict__ VT,
        unsigned short* __restrict__ Y)   // [B*T, C] bf16
{
    const int qblk = (int)(gridDim.x - 1 - blockIdx.x);   // heavy-first (LPT)
    const int bh = blockIdx.y;
    const int tid = threadIdx.x;
    const int w = tid >> 6;
    const int lane = tid & 63;
    const int l16 = lane & 15;
    const int quad = lane >> 4;

    const unsigned short* Qp = Q + (size_t)bh * TT * DD;
    const unsigned short* Kp = K + (size_t)bh * TT * DD;
    const _Float16* Vp = VT + (size_t)bh * DD * TT;

    __shared__ unsigned short Kl[64][64];   // [key][d] bf16, swizzled chunks
    __shared__ _Float16 Vl[64][64];         // [d][t]   fp16, swizzled chunks
    __shared__ unsigned short Ylds[4][16][72];

    const int q = qblk * 64 + w * 16 + l16;

    // Q fragment (B-operand of S^T): B[k=d=quad*8+j][n=q=l16], kept in regs
    frag_b16 bq[2];
#pragma unroll
    for (int dk = 0; dk < 2; ++dk)
        bq[dk] = *reinterpret_cast<const frag_b16*>(
            Qp + (size_t)q * DD + dk * 32 + quad * 8);

    f32x4 yacc[4] = {};   // Y^T[d=dt*16+quad*4+g][q=l16]
    float m = -INFINITY, l = 0.f;

    // staging indices (2 chunks per tensor per thread)
    const int ca = tid, cb = tid + 256;
    const int ra = ca >> 3, oa = ((ca & 7) ^ (ra & 7)) * 8;
    const int rb = cb >> 3, ob = ((cb & 7) ^ (rb & 7)) * 8;
    const int sw = (l16 & 7);   // read-side swizzle key

    for (int it = 0; it <= qblk; ++it) {
        const int j0 = it * 64;
        gl_lds16(Kp + (size_t)(j0 + ra) * DD + oa, (unsigned short*)Kl + ca * 8);
        gl_lds16(Kp + (size_t)(j0 + rb) * DD + ob, (unsigned short*)Kl + cb * 8);
        gl_lds16(Vp + (size_t)ra * TT + j0 + oa, (_Float16*)Vl + ca * 8);
        gl_lds16(Vp + (size_t)rb * TT + j0 + ob, (_Float16*)Vl + cb * 8);
        __syncthreads();

        // S^T[key][q] = K·Q^T
        f32x4 s[4];
#pragma unroll
        for (int mt = 0; mt < 4; ++mt) {
            frag_b16 ak0 = *reinterpret_cast<const frag_b16*>(
                &Kl[mt * 16 + l16][(quad ^ sw) * 8]);
            frag_b16 ak1 = *reinterpret_cast<const frag_b16*>(
                &Kl[mt * 16 + l16][((4 + quad) ^ sw) * 8]);
            f32x4 t = {};
            t = __builtin_amdgcn_mfma_f32_16x16x32_bf16(ak0, bq[0], t, 0, 0, 0);
            t = __builtin_amdgcn_mfma_f32_16x16x32_bf16(ak1, bq[1], t, 0, 0, 0);
            s[mt] = t;
        }

        // scale (+ causal mask on diagonal tile only) + row max
        float nm = -INFINITY;
        if (it == qblk) {
#pragma unroll
            for (int mt = 0; mt < 4; ++mt)
#pragma unroll
                for (int g = 0; g < 4; ++g) {
                    int key = j0 + mt * 16 + quad * 4 + g;
                    float v = s[mt][g] * 0.125f;
                    if (key > q) v = -1e30f;
                    s[mt][g] = v;
                    nm = fmaxf(nm, v);
                }
        } else {
#pragma unroll
            for (int mt = 0; mt < 4; ++mt)
#pragma unroll
                for (int g = 0; g < 4; ++g) {
                    float v = s[mt][g] * 0.125f;
                    s[mt][g] = v;
                    nm = fmaxf(nm, v);
                }
        }
        nm = fmaxf(nm, __shfl_xor(nm, 16));
        nm = fmaxf(nm, __shfl_xor(nm, 32));

        float mn = fmaxf(m, nm);
        float alpha = __expf(m - mn);
        m = mn;

        float rs = 0.f;
#pragma unroll
        for (int mt = 0; mt < 4; ++mt)
#pragma unroll
            for (int g = 0; g < 4; ++g) {
                float e = __expf(s[mt][g] - m);
                s[mt][g] = e;
                rs += e;
            }
        rs += __shfl_xor(rs, 16);
        rs += __shfl_xor(rs, 32);
        l = l * alpha + rs;

        // pack P^T to fp16 B-fragments: B[k=key=quad*4+j][n=q=l16]
        f16x4 pb[4];
#pragma unroll
        for (int kt = 0; kt < 4; ++kt)
#pragma unroll
            for (int g = 0; g < 4; ++g)
                pb[kt][g] = (_Float16)s[kt][g];

        // Y^T += V^T·P^T ; V^T frag A[m=d=l16][k=key=quad*4+j] from LDS
#pragma unroll
        for (int dt = 0; dt < 4; ++dt) {
            f32x4 ya = yacc[dt];
#pragma unroll
            for (int g = 0; g < 4; ++g) ya[g] *= alpha;
#pragma unroll
            for (int kt = 0; kt < 4; ++kt) {
                int colp = (kt * 2 + (quad >> 1)) ^ sw;
                f16x4 av = *reinterpret_cast<const f16x4*>(
                    &Vl[dt * 16 + l16][colp * 8 + (quad & 1) * 4]);
                ya = __builtin_amdgcn_mfma_f32_16x16x16f16(av, pb[kt], ya, 0, 0, 0);
            }
            yacc[dt] = ya;
        }
        __syncthreads();
    }

    // epilogue: normalize, per-wave LDS transpose, coalesced 16B stores
    float rl = 1.f / l;
#pragma unroll
    for (int dt = 0; dt < 4; ++dt)
#pragma unroll
        for (int g = 0; g < 4; ++g)
            Ylds[w][l16][dt * 16 + quad * 4 + g] = f2bf(yacc[dt][g] * rl);

    __syncthreads();

    const int b_ = bh >> 4, h = bh & (HH - 1);
#pragma unroll
    for (int i = 0; i < 2; ++i) {
        int idx = i * 64 + lane;          // 128 us8-chunks per wave tile
        int r = idx >> 3, c8 = (idx & 7) * 8;
        us8 v = *reinterpret_cast<const us8*>(&Ylds[w][r][c8]);
        *reinterpret_cast<us8*>(
            &Y[(size_t)(b_ * TT + qblk * 64 + w * 16 + r) * CC + h * DD + c8]) = v;
    }
}

// --------------------------------------------------------- output projection
__global__ __launch_bounds__(256, 2) void out_gemm(
        const unsigned short* __restrict__ Y,
        const unsigned short* __restrict__ Wo,
        const float* __restrict__ bo,
        float* __restrict__ out)
{
    const int tid = threadIdx.x;
    const int wave = tid >> 6;
    const int lane = tid & 63;
    const int l16 = lane & 15;
    const int quad = lane >> 4;

    const int bx = blockIdx.x * 128;
    const int by = blockIdx.y * 128;
    const int row0 = bx + (wave >> 1) * 64;
    const int col0 = by + (wave & 1) * 64;

    __shared__ unsigned short Xa[128][32];
    __shared__ unsigned short Wb[128][32];

    f32x4 acc[4][4] = {};

    const int c0 = tid, c1 = tid + 256;
    const int r0s = c0 >> 2, o0s = (c0 & 3) * 8;
    const int r1s = c1 >> 2, o1s = (c1 & 3) * 8;

    for (int kk = 0; kk < KDIM; kk += 32) {
        gl_lds16(Y  + (size_t)(bx + r0s) * KDIM + kk + o0s, (unsigned short*)Xa + c0 * 8);
        gl_lds16(Y  + (size_t)(bx + r1s) * KDIM + kk + o1s, (unsigned short*)Xa + c1 * 8);
        gl_lds16(Wo + (size_t)(by + r0s) * KDIM + kk + o0s, (unsigned short*)Wb + c0 * 8);
        gl_lds16(Wo + (size_t)(by + r1s) * KDIM + kk + o1s, (unsigned short*)Wb + c1 * 8);
        __syncthreads();

        frag_b16 a[4], b[4];
#pragma unroll
        for (int r = 0; r < 4; ++r)
            a[r] = *reinterpret_cast<const frag_b16*>(
                &Xa[(wave >> 1) * 64 + r * 16 + l16][quad * 8]);
#pragma unroll
        for (int c = 0; c < 4; ++c)
            b[c] = *reinterpret_cast<const frag_b16*>(
                &Wb[(wave & 1) * 64 + c * 16 + l16][quad * 8]);
#pragma unroll
        for (int r = 0; r < 4; ++r)
#pragma unroll
            for (int c = 0; c < 4; ++c)
                acc[r][c] = __builtin_amdgcn_mfma_f32_16x16x32_bf16(a[r], b[c], acc[r][c], 0, 0, 0);
        __syncthreads();
    }

#pragma unroll
    for (int r = 0; r < 4; ++r)
#pragma unroll
        for (int c = 0; c < 4; ++c)
#pragma unroll
            for (int g = 0; g < 4; ++g) {
                int n = row0 + r * 16 + quad * 4 + g;
                int o = col0 + c * 16 + l16;
                out[(size_t)n * CC + o] = acc[r][c][g] + bo[o];
            }
}

// ---------------------------------------------------------------------- launch
extern "C" void kernel_launch(void* const* d_in, const int* in_sizes, int n_in,
                              void* d_out, int out_size, void* d_ws, size_t ws_size,
                              hipStream_t stream) {
    const float* x  = (const float*)d_in[0];
    const float* Wq = (const float*)d_in[1];
    const float* bq = (const float*)d_in[2];
    const float* Wk = (const float*)d_in[3];
    const float* bk = (const float*)d_in[4];
    const float* Wv = (const float*)d_in[5];
    const float* bv = (const float*)d_in[6];
    const float* Wo = (const float*)d_in[7];
    const float* bo = (const float*)d_in[8];
    float* out = (float*)d_out;

    unsigned short* ws = (unsigned short*)d_ws;
    const size_t NX = (size_t)MROWS * CC;      // 4194304
    const size_t NW = (size_t)CC * CC;         // 1048576
    unsigned short* xb  = ws;
    unsigned short* wqb = xb  + NX;
    unsigned short* wkb = wqb + NW;
    unsigned short* wvb = wkb + NW;
    unsigned short* wob = wvb + NW;
    unsigned short* Qr  = wob + NW;
    unsigned short* Kr  = Qr  + NX;
    _Float16*       VTb = (_Float16*)(Kr + NX);
    unsigned short* Yb  = (unsigned short*)(VTb + NX);

    cvt4<<<dim3((unsigned)(NX / 1024)), 256, 0, stream>>>(x,  xb,  (int)NX);
    cvt4<<<dim3((unsigned)(NW / 1024)), 256, 0, stream>>>(Wq, wqb, (int)NW);
    cvt4<<<dim3((unsigned)(NW / 1024)), 256, 0, stream>>>(Wk, wkb, (int)NW);
    cvt4<<<dim3((unsigned)(NW / 1024)), 256, 0, stream>>>(Wv, wvb, (int)NW);
    cvt4<<<dim3((unsigned)(NW / 1024)), 256, 0, stream>>>(Wo, wob, (int)NW);

    qkv_gemm_rope<<<dim3(MROWS / 128, CC / 128, 3), 256, 0, stream>>>(
        xb, wqb, wkb, wvb, bq, bk, bv, Qr, Kr, VTb);

    attn<<<dim3(TT / 64, BB * HH), 256, 0, stream>>>(Qr, Kr, VTb, Yb);

    out_gemm<<<dim3(MROWS / 128, CC / 128), 256, 0, stream>>>(Yb, wob, bo, out);
}

// Round 6
// 189.954 us; speedup vs baseline: 3.0120x; 1.1198x over previous
//
#include <hip/hip_runtime.h>

// Problem constants (fixed by setup_inputs)
#define BB 2
#define TT 2048
#define CC 1024
#define HH 16
#define DD 64
#define KDIM 1024
#define MROWS (BB*TT)   // 4096

typedef __attribute__((ext_vector_type(8))) short  frag_b16;  // 8 bf16 (4 VGPRs)
typedef __attribute__((ext_vector_type(4))) float  f32x4;
typedef __attribute__((ext_vector_type(4))) unsigned short us4;
typedef __attribute__((ext_vector_type(8))) unsigned short us8;
typedef __attribute__((ext_vector_type(4))) _Float16 f16x4;
typedef __attribute__((ext_vector_type(8))) _Float16 f16x8;

__device__ __forceinline__ unsigned short f2bf(float f) {
    unsigned int u = __builtin_bit_cast(unsigned int, f);
    u += 0x7FFFu + ((u >> 16) & 1u);   // RNE
    return (unsigned short)(u >> 16);
}

// async global->LDS, 16B per lane. LDS dest must be lane-linear.
__device__ __forceinline__ void gl_lds16(const void* g, void* l) {
    __builtin_amdgcn_global_load_lds(
        (const __attribute__((address_space(1))) unsigned int*)g,
        (__attribute__((address_space(3))) unsigned int*)l, 16, 0, 0);
}

// ------------------------------------------- fp32 -> bf16, all 5 tensors fused
// dst layout: x(NX) | Wq(NW) | Wk(NW) | Wv(NW) | Wo(NW)  == ws layout
__global__ __launch_bounds__(256) void cvt_all(
        const float* __restrict__ x,  const float* __restrict__ w0,
        const float* __restrict__ w1, const float* __restrict__ w2,
        const float* __restrict__ w3, unsigned short* __restrict__ dst) {
    const size_t NX = (size_t)MROWS * CC;
    const size_t NW = (size_t)CC * CC;   // 2^20
    size_t i = ((size_t)blockIdx.x * 256 + threadIdx.x) * 4;
    const float* src; size_t off;
    if (i < NX) { src = x; off = i; }
    else {
        size_t j = i - NX;
        int t = (int)(j >> 20);
        src = (t == 0) ? w0 : (t == 1) ? w1 : (t == 2) ? w2 : w3;
        off = j & (NW - 1);
    }
    float4 f = *reinterpret_cast<const float4*>(src + off);
    us4 o;
    o.x = f2bf(f.x); o.y = f2bf(f.y); o.z = f2bf(f.z); o.w = f2bf(f.w);
    *reinterpret_cast<us4*>(dst + i) = o;
}

// ------------------------------------------------- QKV projection (+RoPE) GEMM
// m97 anatomy; V-transpose scratch unioned with the staging LDS (saves 16KB).
// Q output is pre-scaled by 1/8 (rotation preserves scale) so attn drops it.
__global__ __launch_bounds__(256, 3) void qkv_gemm_rope(
        const unsigned short* __restrict__ X,
        const unsigned short* __restrict__ Wq,
        const unsigned short* __restrict__ Wk,
        const unsigned short* __restrict__ Wv,
        const float* __restrict__ bq, const float* __restrict__ bk,
        const float* __restrict__ bv,
        unsigned short* __restrict__ Qo,   // [B,H,T,D] bf16 (roped, /8)
        unsigned short* __restrict__ Ko,   // [B,H,T,D] bf16 (roped)
        _Float16* __restrict__ VTo)        // [B,H,D,T] fp16
{
    const int z = blockIdx.z;
    const unsigned short* W = (z == 0) ? Wq : (z == 1) ? Wk : Wv;
    const float* bias = (z == 0) ? bq : (z == 1) ? bk : bv;

    const int tid = threadIdx.x;
    const int wave = tid >> 6;
    const int lane = tid & 63;
    const int l16 = lane & 15;
    const int quad = lane >> 4;

    const int bx = blockIdx.x * 128;
    const int by = blockIdx.y * 128;
    const int row0 = bx + (wave >> 1) * 64;
    const int col0 = by + (wave & 1) * 64;

    __shared__ __align__(16) char smem[36864];
    unsigned short (*Xa)[32] = (unsigned short(*)[32])smem;            //  8 KB
    unsigned short (*Wb)[32] = (unsigned short(*)[32])(smem + 8192);   //  8 KB
    _Float16 (*Vl)[64][72] = (_Float16(*)[64][72])smem;                // 36 KB, post-loop

    f32x4 acc[4][4] = {};

    const int c0 = tid, c1 = tid + 256;
    const int r0s = c0 >> 2, o0s = (c0 & 3) * 8;
    const int r1s = c1 >> 2, o1s = (c1 & 3) * 8;

    for (int kk = 0; kk < KDIM; kk += 32) {
        gl_lds16(X + (size_t)(bx + r0s) * KDIM + kk + o0s, (unsigned short*)Xa + c0 * 8);
        gl_lds16(X + (size_t)(bx + r1s) * KDIM + kk + o1s, (unsigned short*)Xa + c1 * 8);
        gl_lds16(W + (size_t)(by + r0s) * KDIM + kk + o0s, (unsigned short*)Wb + c0 * 8);
        gl_lds16(W + (size_t)(by + r1s) * KDIM + kk + o1s, (unsigned short*)Wb + c1 * 8);
        __syncthreads();

        frag_b16 a[4], b[4];
#pragma unroll
        for (int r = 0; r < 4; ++r)
            a[r] = *reinterpret_cast<const frag_b16*>(
                &Xa[(wave >> 1) * 64 + r * 16 + l16][quad * 8]);
#pragma unroll
        for (int c = 0; c < 4; ++c)
            b[c] = *reinterpret_cast<const frag_b16*>(
                &Wb[(wave & 1) * 64 + c * 16 + l16][quad * 8]);
#pragma unroll
        for (int r = 0; r < 4; ++r)
#pragma unroll
            for (int c = 0; c < 4; ++c)
                acc[r][c] = __builtin_amdgcn_mfma_f32_16x16x32_bf16(a[r], b[c], acc[r][c], 0, 0, 0);
        __syncthreads();
    }

    if (z == 2) {
        // V: per-wave LDS transpose then coalesced V^T stores (64 tok x 64 d).
#pragma unroll
        for (int r = 0; r < 4; ++r)
#pragma unroll
            for (int c = 0; c < 4; ++c) {
                f16x4 pk;
#pragma unroll
                for (int g = 0; g < 4; ++g)
                    pk[g] = (_Float16)(acc[r][c][g] + bias[col0 + c * 16 + l16]);
                *reinterpret_cast<f16x4*>(&Vl[wave][c * 16 + l16][r * 16 + quad * 4]) = pk;
            }
        const int b_ = row0 >> 11;
        const int t_base = row0 & (TT - 1);
        const int h = col0 >> 6;
        const int dl = lane >> 3;          // 0..7
        const int t8 = (lane & 7) * 8;     // 16B chunk along t
        __builtin_amdgcn_s_waitcnt(0);     // drain own ds_writes (wave-private buf)
#pragma unroll
        for (int i = 0; i < 8; ++i) {
            int d = i * 8 + dl;
            f16x8 v = *reinterpret_cast<const f16x8*>(&Vl[wave][d][t8]);
            *reinterpret_cast<f16x8*>(
                &VTo[((size_t)(b_ * HH + h) * DD + d) * TT + t_base + t8]) = v;
        }
    } else {
        const float qscale = (z == 0) ? 0.125f : 1.0f;
#pragma unroll
        for (int r = 0; r < 4; ++r)
#pragma unroll
            for (int c = 0; c < 4; ++c)
#pragma unroll
                for (int g = 0; g < 4; ++g) {
                    int n = row0 + r * 16 + quad * 4 + g;
                    int o = col0 + c * 16 + l16;
                    float v = acc[r][c][g] + bias[o];
                    int b_ = n >> 11;
                    int t  = n & (TT - 1);
                    int h  = o >> 6;
                    int d  = o & (DD - 1);
                    float pv = __shfl_xor(v, 1);
                    float inv = __expf(-(float)(d & ~1) * (9.210340371976184f / (float)DD));
                    float ang = (float)t * inv;
                    float sn, cs;
                    __sincosf(ang, &sn, &cs);
                    float outv = (d & 1) ? (pv * sn + v * cs) : (v * cs - pv * sn);
                    unsigned short* dst = (z == 0) ? Qo : Ko;
                    dst[((size_t)(b_ * HH + h) * TT + t) * DD + d] = f2bf(outv * qscale);
                }
    }
}

// ------------------------------------------------------------ flash attention
// Paired q-tiles for perfect balance: block handles qblk=pair then 31-pair ->
// every block runs exactly 33 key-tile iterations; 512 uniform blocks = 2/CU.
// Double-buffered LDS staging (global_load_lds 16B, XOR-swizzled gather):
// ONE barrier per iteration, prefetch of tile i+1 overlaps compute of tile i.
// S^T = K·Q^T (q=lane&15 -> lane-local softmax stats); P^T stays in registers
// as the PV B-fragment (Y^T = V^T·P^T, f16 K=16). Q pre-scaled by 1/8.
__global__ __launch_bounds__(256, 2) void attn(
        const unsigned short* __restrict__ Q,
        const unsigned short* __restrict__ K,
        const _Float16* __restrict__ VT,
        unsigned short* __restrict__ Y)   // [B*T, C] bf16
{
    const int pair = blockIdx.x;   // 0..15
    const int bh = blockIdx.y;
    const int tid = threadIdx.x;
    const int w = tid >> 6;
    const int lane = tid & 63;
    const int l16 = lane & 15;
    const int quad = lane >> 4;

    const unsigned short* Qp = Q + (size_t)bh * TT * DD;
    const unsigned short* Kp = K + (size_t)bh * TT * DD;
    const _Float16* Vp = VT + (size_t)bh * DD * TT;

    __shared__ unsigned short Kl[2][64][64];   // [key][d] bf16, swizzled chunks
    __shared__ _Float16 Vl[2][64][64];         // [d][t]   fp16, swizzled chunks
    __shared__ unsigned short Ylds[4][16][72];

    // staging indices (2 chunks per tensor per thread, 512 chunks/buffer)
    const int ca = tid, cb = tid + 256;
    const int ra = ca >> 3, oa = ((ca & 7) ^ (ra & 7)) * 8;
    const int rb = cb >> 3, ob = ((cb & 7) ^ (rb & 7)) * 8;
    const int sw = (l16 & 7);   // read-side swizzle key

    const int b_ = bh >> 4, h = bh & (HH - 1);

#pragma unroll 1
    for (int seg = 0; seg < 2; ++seg) {
        const int qblk = seg ? (31 - pair) : pair;
        const int q0 = qblk * 64;
        const int q = q0 + w * 16 + l16;

        // Q fragment (B-operand of S^T): B[k=d=quad*8+j][n=q=l16]
        frag_b16 bq[2];
#pragma unroll
        for (int dk = 0; dk < 2; ++dk)
            bq[dk] = *reinterpret_cast<const frag_b16*>(
                Qp + (size_t)q * DD + dk * 32 + quad * 8);

        f32x4 yacc[4] = {};   // Y^T[d=dt*16+quad*4+g][q=l16]
        float m = -INFINITY, l = 0.f;

        const int ntiles = qblk + 1;

        // prefetch tile 0 into buffer 0
        gl_lds16(Kp + (size_t)ra * DD + oa, (unsigned short*)&Kl[0][0][0] + ca * 8);
        gl_lds16(Kp + (size_t)rb * DD + ob, (unsigned short*)&Kl[0][0][0] + cb * 8);
        gl_lds16(Vp + (size_t)ra * TT + oa, (_Float16*)&Vl[0][0][0] + ca * 8);
        gl_lds16(Vp + (size_t)rb * TT + ob, (_Float16*)&Vl[0][0][0] + cb * 8);

#pragma unroll 1
        for (int it = 0; it < ntiles; ++it) {
            __syncthreads();   // buf[it&1] ready; buf[(it+1)&1] no longer read
            const int bsel = it & 1;
            if (it + 1 < ntiles) {
                const int jn = (it + 1) * 64;
                const int bn = bsel ^ 1;
                gl_lds16(Kp + (size_t)(jn + ra) * DD + oa, (unsigned short*)&Kl[bn][0][0] + ca * 8);
                gl_lds16(Kp + (size_t)(jn + rb) * DD + ob, (unsigned short*)&Kl[bn][0][0] + cb * 8);
                gl_lds16(Vp + (size_t)ra * TT + jn + oa, (_Float16*)&Vl[bn][0][0] + ca * 8);
                gl_lds16(Vp + (size_t)rb * TT + jn + ob, (_Float16*)&Vl[bn][0][0] + cb * 8);
            }
            const int j0 = it * 64;

            // S^T[key][q] = K·Q^T  (Q carries the 1/8 scale)
            f32x4 s[4];
#pragma unroll
            for (int mt = 0; mt < 4; ++mt) {
                frag_b16 ak0 = *reinterpret_cast<const frag_b16*>(
                    &Kl[bsel][mt * 16 + l16][(quad ^ sw) * 8]);
                frag_b16 ak1 = *reinterpret_cast<const frag_b16*>(
                    &Kl[bsel][mt * 16 + l16][((4 + quad) ^ sw) * 8]);
                f32x4 t = {};
                t = __builtin_amdgcn_mfma_f32_16x16x32_bf16(ak0, bq[0], t, 0, 0, 0);
                t = __builtin_amdgcn_mfma_f32_16x16x32_bf16(ak1, bq[1], t, 0, 0, 0);
                s[mt] = t;
            }

            // causal mask (diagonal tile only) + row max
            float nm = -INFINITY;
            if (it == qblk) {
#pragma unroll
                for (int mt = 0; mt < 4; ++mt)
#pragma unroll
                    for (int g = 0; g < 4; ++g) {
                        int key = j0 + mt * 16 + quad * 4 + g;
                        float v = s[mt][g];
                        if (key > q) v = -1e30f;
                        s[mt][g] = v;
                        nm = fmaxf(nm, v);
                    }
            } else {
#pragma unroll
                for (int mt = 0; mt < 4; ++mt)
#pragma unroll
                    for (int g = 0; g < 4; ++g)
                        nm = fmaxf(nm, s[mt][g]);
            }
            nm = fmaxf(nm, __shfl_xor(nm, 16));
            nm = fmaxf(nm, __shfl_xor(nm, 32));

            float mn = fmaxf(m, nm);
            float alpha = __expf(m - mn);
            m = mn;

            float rs = 0.f;
#pragma unroll
            for (int mt = 0; mt < 4; ++mt)
#pragma unroll
                for (int g = 0; g < 4; ++g) {
                    float e = __expf(s[mt][g] - m);
                    s[mt][g] = e;
                    rs += e;
                }
            rs += __shfl_xor(rs, 16);
            rs += __shfl_xor(rs, 32);
            l = l * alpha + rs;

            // pack P^T to fp16 B-fragments: B[k=key=quad*4+j][n=q=l16]
            f16x4 pb[4];
#pragma unroll
            for (int kt = 0; kt < 4; ++kt)
#pragma unroll
                for (int g = 0; g < 4; ++g)
                    pb[kt][g] = (_Float16)s[kt][g];

            // Y^T += V^T·P^T ; V^T frag A[m=d=l16][k=key=quad*4+j] from LDS
#pragma unroll
            for (int dt = 0; dt < 4; ++dt) {
                f32x4 ya = yacc[dt];
#pragma unroll
                for (int g = 0; g < 4; ++g) ya[g] *= alpha;
#pragma unroll
                for (int kt = 0; kt < 4; ++kt) {
                    int colp = (kt * 2 + (quad >> 1)) ^ sw;
                    f16x4 av = *reinterpret_cast<const f16x4*>(
                        &Vl[bsel][dt * 16 + l16][colp * 8 + (quad & 1) * 4]);
                    ya = __builtin_amdgcn_mfma_f32_16x16x16f16(av, pb[kt], ya, 0, 0, 0);
                }
                yacc[dt] = ya;
            }
        }

        __syncthreads();   // all waves done with K/V buffers before next seg's DMA

        // epilogue: normalize, per-wave LDS transpose, coalesced 16B stores
        float rl = 1.f / l;
#pragma unroll
        for (int dt = 0; dt < 4; ++dt)
#pragma unroll
            for (int g = 0; g < 4; ++g)
                Ylds[w][l16][dt * 16 + quad * 4 + g] = f2bf(yacc[dt][g] * rl);

        // wave-private Ylds[w]: same-wave ds_write->ds_read, lgkmcnt handles it
#pragma unroll
        for (int i = 0; i < 2; ++i) {
            int idx = i * 64 + lane;
            int r = idx >> 3, c8 = (idx & 7) * 8;
            us8 v = *reinterpret_cast<const us8*>(&Ylds[w][r][c8]);
            *reinterpret_cast<us8*>(
                &Y[(size_t)(b_ * TT + q0 + w * 16 + r) * CC + h * DD + c8]) = v;
        }
    }
}

// --------------------------------------------------------- output projection
__global__ __launch_bounds__(256, 2) void out_gemm(
        const unsigned short* __restrict__ Y,
        const unsigned short* __restrict__ Wo,
        const float* __restrict__ bo,
        float* __restrict__ out)
{
    const int tid = threadIdx.x;
    const int wave = tid >> 6;
    const int lane = tid & 63;
    const int l16 = lane & 15;
    const int quad = lane >> 4;

    const int bx = blockIdx.x * 128;
    const int by = blockIdx.y * 128;
    const int row0 = bx + (wave >> 1) * 64;
    const int col0 = by + (wave & 1) * 64;

    __shared__ unsigned short Xa[128][32];
    __shared__ unsigned short Wb[128][32];

    f32x4 acc[4][4] = {};

    const int c0 = tid, c1 = tid + 256;
    const int r0s = c0 >> 2, o0s = (c0 & 3) * 8;
    const int r1s = c1 >> 2, o1s = (c1 & 3) * 8;

    for (int kk = 0; kk < KDIM; kk += 32) {
        gl_lds16(Y  + (size_t)(bx + r0s) * KDIM + kk + o0s, (unsigned short*)Xa + c0 * 8);
        gl_lds16(Y  + (size_t)(bx + r1s) * KDIM + kk + o1s, (unsigned short*)Xa + c1 * 8);
        gl_lds16(Wo + (size_t)(by + r0s) * KDIM + kk + o0s, (unsigned short*)Wb + c0 * 8);
        gl_lds16(Wo + (size_t)(by + r1s) * KDIM + kk + o1s, (unsigned short*)Wb + c1 * 8);
        __syncthreads();

        frag_b16 a[4], b[4];
#pragma unroll
        for (int r = 0; r < 4; ++r)
            a[r] = *reinterpret_cast<const frag_b16*>(
                &Xa[(wave >> 1) * 64 + r * 16 + l16][quad * 8]);
#pragma unroll
        for (int c = 0; c < 4; ++c)
            b[c] = *reinterpret_cast<const frag_b16*>(
                &Wb[(wave & 1) * 64 + c * 16 + l16][quad * 8]);
#pragma unroll
        for (int r = 0; r < 4; ++r)
#pragma unroll
            for (int c = 0; c < 4; ++c)
                acc[r][c] = __builtin_amdgcn_mfma_f32_16x16x32_bf16(a[r], b[c], acc[r][c], 0, 0, 0);
        __syncthreads();
    }

#pragma unroll
    for (int r = 0; r < 4; ++r)
#pragma unroll
        for (int c = 0; c < 4; ++c)
#pragma unroll
            for (int g = 0; g < 4; ++g) {
                int n = row0 + r * 16 + quad * 4 + g;
                int o = col0 + c * 16 + l16;
                out[(size_t)n * CC + o] = acc[r][c][g] + bo[o];
            }
}

// ---------------------------------------------------------------------- launch
extern "C" void kernel_launch(void* const* d_in, const int* in_sizes, int n_in,
                              void* d_out, int out_size, void* d_ws, size_t ws_size,
                              hipStream_t stream) {
    const float* x  = (const float*)d_in[0];
    const float* Wq = (const float*)d_in[1];
    const float* bq = (const float*)d_in[2];
    const float* Wk = (const float*)d_in[3];
    const float* bk = (const float*)d_in[4];
    const float* Wv = (const float*)d_in[5];
    const float* bv = (const float*)d_in[6];
    const float* Wo = (const float*)d_in[7];
    const float* bo = (const float*)d_in[8];
    float* out = (float*)d_out;

    unsigned short* ws = (unsigned short*)d_ws;
    const size_t NX = (size_t)MROWS * CC;      // 4194304
    const size_t NW = (size_t)CC * CC;         // 1048576
    unsigned short* xb  = ws;
    unsigned short* wqb = xb  + NX;
    unsigned short* wkb = wqb + NW;
    unsigned short* wvb = wkb + NW;
    unsigned short* wob = wvb + NW;
    unsigned short* Qr  = wob + NW;
    unsigned short* Kr  = Qr  + NX;
    _Float16*       VTb = (_Float16*)(Kr + NX);
    unsigned short* Yb  = (unsigned short*)(VTb + NX);

    const size_t NALL = NX + 4 * NW;           // 8388608
    cvt_all<<<dim3((unsigned)(NALL / 1024)), 256, 0, stream>>>(x, Wq, Wk, Wv, Wo, xb);

    qkv_gemm_rope<<<dim3(MROWS / 128, CC / 128, 3), 256, 0, stream>>>(
        xb, wqb, wkb, wvb, bq, bk, bv, Qr, Kr, VTb);

    attn<<<dim3(16, BB * HH), 256, 0, stream>>>(Qr, Kr, VTb, Yb);

    out_gemm<<<dim3(MROWS / 128, CC / 128), 256, 0, stream>>>(Yb, wob, bo, out);
}

// Round 8
// 183.464 us; speedup vs baseline: 3.1186x; 1.0354x over previous
//
#include <hip/hip_runtime.h>

// Problem constants (fixed by setup_inputs)
#define BB 2
#define TT 2048
#define CC 1024
#define HH 16
#define DD 64
#define KDIM 1024
#define MROWS (BB*TT)   // 4096

typedef __attribute__((ext_vector_type(8))) short  frag_b16;  // 8 bf16 (4 VGPRs)
typedef __attribute__((ext_vector_type(4))) float  f32x4;
typedef __attribute__((ext_vector_type(4))) unsigned short us4;
typedef __attribute__((ext_vector_type(8))) unsigned short us8;
typedef __attribute__((ext_vector_type(4))) _Float16 f16x4;
typedef __attribute__((ext_vector_type(8))) _Float16 f16x8;

#define EXP2F(x) __builtin_amdgcn_exp2f(x)   // v_exp_f32 (base-2)

__device__ __forceinline__ unsigned short f2bf(float f) {
    unsigned int u = __builtin_bit_cast(unsigned int, f);
    u += 0x7FFFu + ((u >> 16) & 1u);   // RNE
    return (unsigned short)(u >> 16);
}

// async global->LDS, 16B per lane. LDS dest must be lane-linear.
__device__ __forceinline__ void gl_lds16(const void* g, void* l) {
    __builtin_amdgcn_global_load_lds(
        (const __attribute__((address_space(1))) unsigned int*)g,
        (__attribute__((address_space(3))) unsigned int*)l, 16, 0, 0);
}

// ------------------------------------------- fp32 -> bf16, all 5 tensors fused
__global__ __launch_bounds__(256) void cvt_all(
        const float* __restrict__ x,  const float* __restrict__ w0,
        const float* __restrict__ w1, const float* __restrict__ w2,
        const float* __restrict__ w3, unsigned short* __restrict__ dst) {
    const size_t NX = (size_t)MROWS * CC;
    const size_t NW = (size_t)CC * CC;   // 2^20
    size_t i = ((size_t)blockIdx.x * 256 + threadIdx.x) * 4;
    const float* src; size_t off;
    if (i < NX) { src = x; off = i; }
    else {
        size_t j = i - NX;
        int t = (int)(j >> 20);
        src = (t == 0) ? w0 : (t == 1) ? w1 : (t == 2) ? w2 : w3;
        off = j & (NW - 1);
    }
    float4 f = *reinterpret_cast<const float4*>(src + off);
    us4 o;
    o.x = f2bf(f.x); o.y = f2bf(f.y); o.z = f2bf(f.z); o.w = f2bf(f.w);
    *reinterpret_cast<us4*>(dst + i) = o;
}

// ------------------------------------------------- QKV projection (+RoPE) GEMM
// Q output carries (1/8)*log2e so attn's softmax runs in pure exp2.
// RoPE epilogue uses incremental rotation: 3 sincos per column instead of 16.
__global__ __launch_bounds__(256, 3) void qkv_gemm_rope(
        const unsigned short* __restrict__ X,
        const unsigned short* __restrict__ Wq,
        const unsigned short* __restrict__ Wk,
        const unsigned short* __restrict__ Wv,
        const float* __restrict__ bq, const float* __restrict__ bk,
        const float* __restrict__ bv,
        unsigned short* __restrict__ Qo,   // [B,H,T,D] bf16 (roped, *0.1803)
        unsigned short* __restrict__ Ko,   // [B,H,T,D] bf16 (roped)
        _Float16* __restrict__ VTo)        // [B,H,D,T] fp16
{
    const int z = blockIdx.z;
    const unsigned short* W = (z == 0) ? Wq : (z == 1) ? Wk : Wv;
    const float* bias = (z == 0) ? bq : (z == 1) ? bk : bv;

    const int tid = threadIdx.x;
    const int wave = tid >> 6;
    const int lane = tid & 63;
    const int l16 = lane & 15;
    const int quad = lane >> 4;

    const int bx = blockIdx.x * 128;
    const int by = blockIdx.y * 128;
    const int row0 = bx + (wave >> 1) * 64;
    const int col0 = by + (wave & 1) * 64;

    __shared__ __align__(16) char smem[36864];
    unsigned short (*Xa)[32] = (unsigned short(*)[32])smem;            //  8 KB
    unsigned short (*Wb)[32] = (unsigned short(*)[32])(smem + 8192);   //  8 KB
    _Float16 (*Vl)[64][72] = (_Float16(*)[64][72])smem;                // 36 KB, post-loop

    f32x4 acc[4][4] = {};

    const int c0 = tid, c1 = tid + 256;
    const int r0s = c0 >> 2, o0s = (c0 & 3) * 8;
    const int r1s = c1 >> 2, o1s = (c1 & 3) * 8;

    for (int kk = 0; kk < KDIM; kk += 32) {
        gl_lds16(X + (size_t)(bx + r0s) * KDIM + kk + o0s, (unsigned short*)Xa + c0 * 8);
        gl_lds16(X + (size_t)(bx + r1s) * KDIM + kk + o1s, (unsigned short*)Xa + c1 * 8);
        gl_lds16(W + (size_t)(by + r0s) * KDIM + kk + o0s, (unsigned short*)Wb + c0 * 8);
        gl_lds16(W + (size_t)(by + r1s) * KDIM + kk + o1s, (unsigned short*)Wb + c1 * 8);
        __syncthreads();

        frag_b16 a[4], b[4];
#pragma unroll
        for (int r = 0; r < 4; ++r)
            a[r] = *reinterpret_cast<const frag_b16*>(
                &Xa[(wave >> 1) * 64 + r * 16 + l16][quad * 8]);
#pragma unroll
        for (int c = 0; c < 4; ++c)
            b[c] = *reinterpret_cast<const frag_b16*>(
                &Wb[(wave & 1) * 64 + c * 16 + l16][quad * 8]);
#pragma unroll
        for (int r = 0; r < 4; ++r)
#pragma unroll
            for (int c = 0; c < 4; ++c)
                acc[r][c] = __builtin_amdgcn_mfma_f32_16x16x32_bf16(a[r], b[c], acc[r][c], 0, 0, 0);
        __syncthreads();
    }

    if (z == 2) {
        // V: per-wave LDS transpose then coalesced V^T stores (64 tok x 64 d).
#pragma unroll
        for (int r = 0; r < 4; ++r)
#pragma unroll
            for (int c = 0; c < 4; ++c) {
                f16x4 pk;
#pragma unroll
                for (int g = 0; g < 4; ++g)
                    pk[g] = (_Float16)(acc[r][c][g] + bias[col0 + c * 16 + l16]);
                *reinterpret_cast<f16x4*>(&Vl[wave][c * 16 + l16][r * 16 + quad * 4]) = pk;
            }
        const int b_ = row0 >> 11;
        const int t_base = row0 & (TT - 1);
        const int h = col0 >> 6;
        const int dl = lane >> 3;          // 0..7
        const int t8 = (lane & 7) * 8;     // 16B chunk along t
        __builtin_amdgcn_s_waitcnt(0);     // drain own ds_writes (wave-private buf)
#pragma unroll
        for (int i = 0; i < 8; ++i) {
            int d = i * 8 + dl;
            f16x8 v = *reinterpret_cast<const f16x8*>(&Vl[wave][d][t8]);
            *reinterpret_cast<f16x8*>(
                &VTo[((size_t)(b_ * HH + h) * DD + d) * TT + t_base + t8]) = v;
        }
    } else {
        const float qsc = (z == 0) ? 0.180336888f : 1.0f;   // (1/8)*log2(e)
        unsigned short* dst = (z == 0) ? Qo : Ko;
        const int b_ = row0 >> 11;
        const int tq0 = (row0 & (TT - 1)) + quad * 4;
#pragma unroll
        for (int c = 0; c < 4; ++c) {
            const int o = col0 + c * 16 + l16;
            const int h = o >> 6, d = o & (DD - 1);
            const float inv = __expf(-(float)(d & ~1) * (9.210340371976184f / (float)DD));
            float cs0, sn0, cs1, sn1, cs16, sn16;
            __sincosf((float)tq0 * inv, &sn0, &cs0);
            __sincosf(inv, &sn1, &cs1);
            __sincosf(16.f * inv, &sn16, &cs16);
            float cr = cs0, sr = sn0;
#pragma unroll
            for (int r = 0; r < 4; ++r) {
                float cg = cr, sg = sr;
#pragma unroll
                for (int g = 0; g < 4; ++g) {
                    int n = row0 + r * 16 + quad * 4 + g;
                    int t = n & (TT - 1);
                    float v = acc[r][c][g] + bias[o];
                    float pv = __shfl_xor(v, 1);
                    float outv = (d & 1) ? (pv * sg + v * cg) : (v * cg - pv * sg);
                    dst[((size_t)(b_ * HH + h) * TT + t) * DD + d] = f2bf(outv * qsc);
                    float cn = cg * cs1 - sg * sn1;   // advance angle by inv
                    sg = sg * cs1 + cg * sn1;
                    cg = cn;
                }
                float crn = cr * cs16 - sr * sn16;    // advance angle by 16*inv
                sr = sr * cs16 + cr * sn16;
                cr = crn;
            }
        }
    }
}

// ------------------------------------------------------------ flash attention
// 1D grid of 512, XCD-grouped: bh=(b&7)*4+((b>>3)&3) -> each XCD serves 4
// heads, K/V working set 2MB fits its private L2. Paired q-tiles (qblk=pair,
// 31-pair) -> every block runs exactly 17 key-tile iterations of 128 keys.
// Double-buffered LDS staging, ONE barrier/iter. S^T = K·Q^T (q=lane&15 ->
// lane-local softmax, base-2: Q pre-scaled by log2e/8, bare v_exp_f32).
// P^T stays in registers as PV B-fragment (Y^T = V^T·P^T, f16 K=16).
__global__ __launch_bounds__(256, 2) void attn(
        const unsigned short* __restrict__ Q,
        const unsigned short* __restrict__ K,
        const _Float16* __restrict__ VT,
        unsigned short* __restrict__ Y)   // [B*T, C] bf16
{
    const int b1d = blockIdx.x;                 // 0..511
    const int bh = (b1d & 7) * 4 + ((b1d >> 3) & 3);
    const int pair = b1d >> 5;                  // 0..15
    const int tid = threadIdx.x;
    const int w = tid >> 6;
    const int lane = tid & 63;
    const int l16 = lane & 15;
    const int quad = lane >> 4;

    const unsigned short* Qp = Q + (size_t)bh * TT * DD;
    const unsigned short* Kp = K + (size_t)bh * TT * DD;
    const _Float16* Vp = VT + (size_t)bh * DD * TT;

    __shared__ unsigned short Kl[2][128][64];   // [key][d] bf16, swizzled chunks
    __shared__ _Float16 Vl[2][64][128];         // [d][t]   fp16, swizzled chunks
    __shared__ unsigned short Ylds[4][16][72];

    const int sw = (l16 & 7);   // read-side swizzle key
    const int b_ = bh >> 4, h = bh & (HH - 1);

#pragma unroll 1
    for (int seg = 0; seg < 2; ++seg) {
        const int qblk = seg ? (31 - pair) : pair;
        const int q0 = qblk * 64;
        const int q = q0 + w * 16 + l16;

        // Q fragment (B-operand of S^T): B[k=d=quad*8+j][n=q=l16]
        frag_b16 bq[2];
#pragma unroll
        for (int dk = 0; dk < 2; ++dk)
            bq[dk] = *reinterpret_cast<const frag_b16*>(
                Qp + (size_t)q * DD + dk * 32 + quad * 8);

        f32x4 yacc[4] = {};   // Y^T[d=dt*16+quad*4+g][q=l16]
        float m = -INFINITY, l = 0.f;

        const int ntiles = (qblk >> 1) + 1;   // 128-key tiles

        // prefetch tile 0 into buffer 0 (4 K-chunks + 4 V-chunks per thread)
#pragma unroll
        for (int i = 0; i < 4; ++i) {
            int n = tid + 256 * i;
            int kr = n >> 3,  kc = ((n & 7)  ^ (kr & 7)) * 8;
            int vr = n >> 4,  vc = ((n & 15) ^ (vr & 7)) * 8;
            gl_lds16(Kp + (size_t)kr * DD + kc, (unsigned short*)&Kl[0][0][0] + n * 8);
            gl_lds16(Vp + (size_t)vr * TT + vc, (_Float16*)&Vl[0][0][0] + n * 8);
        }

#pragma unroll 1
        for (int it = 0; it < ntiles; ++it) {
            __syncthreads();   // buf[it&1] ready; buf[(it+1)&1] no longer read
            const int bsel = it & 1;
            if (it + 1 < ntiles) {
                const int jn = (it + 1) * 128;
                const int bn = bsel ^ 1;
#pragma unroll
                for (int i = 0; i < 4; ++i) {
                    int n = tid + 256 * i;
                    int kr = n >> 3,  kc = ((n & 7)  ^ (kr & 7)) * 8;
                    int vr = n >> 4,  vc = ((n & 15) ^ (vr & 7)) * 8;
                    gl_lds16(Kp + (size_t)(jn + kr) * DD + kc,
                             (unsigned short*)&Kl[bn][0][0] + n * 8);
                    gl_lds16(Vp + (size_t)vr * TT + jn + vc,
                             (_Float16*)&Vl[bn][0][0] + n * 8);
                }
            }
            const int j0 = it * 128;

            // S^T[key][q] = K·Q^T  (Q carries log2e/8)
            f32x4 s[8];
#pragma unroll
            for (int mt = 0; mt < 8; ++mt) {
                frag_b16 ak0 = *reinterpret_cast<const frag_b16*>(
                    &Kl[bsel][mt * 16 + l16][(quad ^ sw) * 8]);
                frag_b16 ak1 = *reinterpret_cast<const frag_b16*>(
                    &Kl[bsel][mt * 16 + l16][((4 + quad) ^ sw) * 8]);
                f32x4 t = {};
                t = __builtin_amdgcn_mfma_f32_16x16x32_bf16(ak0, bq[0], t, 0, 0, 0);
                t = __builtin_amdgcn_mfma_f32_16x16x32_bf16(ak1, bq[1], t, 0, 0, 0);
                s[mt] = t;
            }

            // causal mask (last tile only) + row max
            float nm = -INFINITY;
            if (it == ntiles - 1) {
#pragma unroll
                for (int mt = 0; mt < 8; ++mt)
#pragma unroll
                    for (int g = 0; g < 4; ++g) {
                        int key = j0 + mt * 16 + quad * 4 + g;
                        float v = s[mt][g];
                        if (key > q) v = -1e30f;
                        s[mt][g] = v;
                        nm = fmaxf(nm, v);
                    }
            } else {
#pragma unroll
                for (int mt = 0; mt < 8; ++mt)
#pragma unroll
                    for (int g = 0; g < 4; ++g)
                        nm = fmaxf(nm, s[mt][g]);
            }
            nm = fmaxf(nm, __shfl_xor(nm, 16));
            nm = fmaxf(nm, __shfl_xor(nm, 32));

            float mn = fmaxf(m, nm);
            float alpha = EXP2F(m - mn);
            m = mn;

            float rs = 0.f;
            f16x4 pb[8];
#pragma unroll
            for (int mt = 0; mt < 8; ++mt)
#pragma unroll
                for (int g = 0; g < 4; ++g) {
                    float e = EXP2F(s[mt][g] - m);
                    pb[mt][g] = (_Float16)e;
                    rs += e;
                }
            rs += __shfl_xor(rs, 16);
            rs += __shfl_xor(rs, 32);
            l = l * alpha + rs;

            // Y^T += V^T·P^T ; V^T frag A[m=d=l16][k=key=quad*4+j] from LDS
#pragma unroll
            for (int dt = 0; dt < 4; ++dt) {
                f32x4 ya = yacc[dt];
#pragma unroll
                for (int g = 0; g < 4; ++g) ya[g] *= alpha;
#pragma unroll
                for (int kt = 0; kt < 8; ++kt) {
                    int colp = (kt * 2 + (quad >> 1)) ^ sw;
                    f16x4 av = *reinterpret_cast<const f16x4*>(
                        &Vl[bsel][dt * 16 + l16][colp * 8 + (quad & 1) * 4]);
                    ya = __builtin_amdgcn_mfma_f32_16x16x16f16(av, pb[kt], ya, 0, 0, 0);
                }
                yacc[dt] = ya;
            }
        }

        __syncthreads();   // all waves done with K/V buffers before next seg's DMA

        // epilogue: normalize, per-wave LDS transpose, coalesced 16B stores
        float rl = 1.f / l;
#pragma unroll
        for (int dt = 0; dt < 4; ++dt)
#pragma unroll
            for (int g = 0; g < 4; ++g)
                Ylds[w][l16][dt * 16 + quad * 4 + g] = f2bf(yacc[dt][g] * rl);

#pragma unroll
        for (int i = 0; i < 2; ++i) {
            int idx = i * 64 + lane;
            int r = idx >> 3, c8 = (idx & 7) * 8;
            us8 v = *reinterpret_cast<const us8*>(&Ylds[w][r][c8]);
            *reinterpret_cast<us8*>(
                &Y[(size_t)(b_ * TT + q0 + w * 16 + r) * CC + h * DD + c8]) = v;
        }
    }
}

// --------------------------------------------------------- output projection
__global__ __launch_bounds__(256, 2) void out_gemm(
        const unsigned short* __restrict__ Y,
        const unsigned short* __restrict__ Wo,
        const float* __restrict__ bo,
        float* __restrict__ out)
{
    const int tid = threadIdx.x;
    const int wave = tid >> 6;
    const int lane = tid & 63;
    const int l16 = lane & 15;
    const int quad = lane >> 4;

    const int bx = blockIdx.x * 128;
    const int by = blockIdx.y * 128;
    const int row0 = bx + (wave >> 1) * 64;
    const int col0 = by + (wave & 1) * 64;

    __shared__ unsigned short Xa[128][32];
    __shared__ unsigned short Wb[128][32];

    f32x4 acc[4][4] = {};

    const int c0 = tid, c1 = tid + 256;
    const int r0s = c0 >> 2, o0s = (c0 & 3) * 8;
    const int r1s = c1 >> 2, o1s = (c1 & 3) * 8;

    for (int kk = 0; kk < KDIM; kk += 32) {
        gl_lds16(Y  + (size_t)(bx + r0s) * KDIM + kk + o0s, (unsigned short*)Xa + c0 * 8);
        gl_lds16(Y  + (size_t)(bx + r1s) * KDIM + kk + o1s, (unsigned short*)Xa + c1 * 8);
        gl_lds16(Wo + (size_t)(by + r0s) * KDIM + kk + o0s, (unsigned short*)Wb + c0 * 8);
        gl_lds16(Wo + (size_t)(by + r1s) * KDIM + kk + o1s, (unsigned short*)Wb + c1 * 8);
        __syncthreads();

        frag_b16 a[4], b[4];
#pragma unroll
        for (int r = 0; r < 4; ++r)
            a[r] = *reinterpret_cast<const frag_b16*>(
                &Xa[(wave >> 1) * 64 + r * 16 + l16][quad * 8]);
#pragma unroll
        for (int c = 0; c < 4; ++c)
            b[c] = *reinterpret_cast<const frag_b16*>(
                &Wb[(wave & 1) * 64 + c * 16 + l16][quad * 8]);
#pragma unroll
        for (int r = 0; r < 4; ++r)
#pragma unroll
            for (int c = 0; c < 4; ++c)
                acc[r][c] = __builtin_amdgcn_mfma_f32_16x16x32_bf16(a[r], b[c], acc[r][c], 0, 0, 0);
        __syncthreads();
    }

#pragma unroll
    for (int r = 0; r < 4; ++r)
#pragma unroll
        for (int c = 0; c < 4; ++c)
#pragma unroll
            for (int g = 0; g < 4; ++g) {
                int n = row0 + r * 16 + quad * 4 + g;
                int o = col0 + c * 16 + l16;
                out[(size_t)n * CC + o] = acc[r][c][g] + bo[o];
            }
}

// ---------------------------------------------------------------------- launch
extern "C" void kernel_launch(void* const* d_in, const int* in_sizes, int n_in,
                              void* d_out, int out_size, void* d_ws, size_t ws_size,
                              hipStream_t stream) {
    const float* x  = (const float*)d_in[0];
    const float* Wq = (const float*)d_in[1];
    const float* bq = (const float*)d_in[2];
    const float* Wk = (const float*)d_in[3];
    const float* bk = (const float*)d_in[4];
    const float* Wv = (const float*)d_in[5];
    const float* bv = (const float*)d_in[6];
    const float* Wo = (const float*)d_in[7];
    const float* bo = (const float*)d_in[8];
    float* out = (float*)d_out;

    unsigned short* ws = (unsigned short*)d_ws;
    const size_t NX = (size_t)MROWS * CC;      // 4194304
    const size_t NW = (size_t)CC * CC;         // 1048576
    unsigned short* xb  = ws;
    unsigned short* wqb = xb  + NX;
    unsigned short* wkb = wqb + NW;
    unsigned short* wvb = wkb + NW;
    unsigned short* wob = wvb + NW;
    unsigned short* Qr  = wob + NW;
    unsigned short* Kr  = Qr  + NX;
    _Float16*       VTb = (_Float16*)(Kr + NX);
    unsigned short* Yb  = (unsigned short*)(VTb + NX);

    const size_t NALL = NX + 4 * NW;           // 8388608
    cvt_all<<<dim3((unsigned)(NALL / 1024)), 256, 0, stream>>>(x, Wq, Wk, Wv, Wo, xb);

    qkv_gemm_rope<<<dim3(MROWS / 128, CC / 128, 3), 256, 0, stream>>>(
        xb, wqb, wkb, wvb, bq, bk, bv, Qr, Kr, VTb);

    attn<<<dim3(512), 256, 0, stream>>>(Qr, Kr, VTb, Yb);

    out_gemm<<<dim3(MROWS / 128, CC / 128), 256, 0, stream>>>(Yb, wob, bo, out);
}